// Round 1
// baseline (431.023 us; speedup 1.0000x reference)
//
#include <hip/hip_runtime.h>
#include <hip/hip_bf16.h>

#define DEV __device__ __forceinline__

// Problem constants
constexpr int BB = 4, NQ1 = 1024, DM = 256, NHH = 8, KK = 49;
constexpr int HWP = 4096;          // 64*64
constexpr int NQT = BB * NQ1;      // 4096 queries

DEV unsigned pack_bf16(float a, float b) {
    __hip_bfloat162 h2;
    h2.x = __float2bfloat16(a);
    h2.y = __float2bfloat16(b);
    unsigned u;
    __builtin_memcpy(&u, &h2, 4);
    return u;
}

// ---------------- transpose memory (B,C,H,W) -> memT (B,HW,C) ----------------
__global__ __launch_bounds__(256) void k_transpose(const float* __restrict__ src,
                                                   float* __restrict__ dst) {
    __shared__ float tile[32][33];
    int b = blockIdx.z;
    int c0 = blockIdx.y * 32;
    int p0 = blockIdx.x * 32;
    int tx = threadIdx.x, ty = threadIdx.y;
    const float* s = src + ((size_t)b * DM + c0) * HWP + p0;
#pragma unroll
    for (int i = 0; i < 32; i += 8) tile[ty + i][tx] = s[(size_t)(ty + i) * HWP + tx];
    __syncthreads();
    float* d = dst + ((size_t)b * HWP + p0) * DM + c0;
#pragma unroll
    for (int i = 0; i < 32; i += 8) d[(size_t)(ty + i) * DM + tx] = tile[tx][ty + i];
}

// ---------------- generic fp32 tiled GEMM ----------------
// C[m][n] = act( sum_k A[m][k]*B[k][n] + bias[n] )
// bt==1: B stored N x K (access B[n][k])
// act: 0 none, 1 relu, 2 tanh(x)*(*sclp)
__global__ __launch_bounds__(256) void gemm_f32(
    const float* __restrict__ A, const float* __restrict__ Bm,
    const float* __restrict__ bias, float* __restrict__ C,
    int M, int N, int K, int lda, int ldb, int ldc,
    long Ab, long Bb, long Cb, long biasb,
    const float* __restrict__ sclp, int act, int bt) {
    int z = blockIdx.z;
    A += (long)z * Ab;
    Bm += (long)z * Bb;
    C += (long)z * Cb;
    if (bias) bias += (long)z * biasb;

    __shared__ float As[16][68];
    __shared__ float Bs[16][68];
    int t = threadIdx.x;
    int tx = t & 15, ty = t >> 4;
    int m0 = blockIdx.y * 64, n0 = blockIdx.x * 64;
    float acc[4][4] = {};

    for (int k0 = 0; k0 < K; k0 += 16) {
        // A tile 64x16 (M,K assumed multiples of 64/16)
        {
            int m = t >> 2;
            int kq = (t & 3) * 4;
            float4 a4 = *(const float4*)&A[(size_t)(m0 + m) * lda + k0 + kq];
            As[kq + 0][m] = a4.x;
            As[kq + 1][m] = a4.y;
            As[kq + 2][m] = a4.z;
            As[kq + 3][m] = a4.w;
        }
        if (!bt) {
            int kr = t >> 4;
            int n = (t & 15) * 4;
            int col = n0 + n;
            float4 b4;
            if ((col + 3 < N) && ((ldb & 3) == 0)) {
                b4 = *(const float4*)&Bm[(size_t)(k0 + kr) * ldb + col];
            } else {
                b4.x = (col + 0 < N) ? Bm[(size_t)(k0 + kr) * ldb + col + 0] : 0.f;
                b4.y = (col + 1 < N) ? Bm[(size_t)(k0 + kr) * ldb + col + 1] : 0.f;
                b4.z = (col + 2 < N) ? Bm[(size_t)(k0 + kr) * ldb + col + 2] : 0.f;
                b4.w = (col + 3 < N) ? Bm[(size_t)(k0 + kr) * ldb + col + 3] : 0.f;
            }
            *(float4*)&Bs[kr][n] = b4;
        } else {
            int n = t >> 2;
            int kq = (t & 3) * 4;
            int col = n0 + n;
            float4 b4 = {0.f, 0.f, 0.f, 0.f};
            if (col < N) b4 = *(const float4*)&Bm[(size_t)col * ldb + k0 + kq];
            Bs[kq + 0][n] = b4.x;
            Bs[kq + 1][n] = b4.y;
            Bs[kq + 2][n] = b4.z;
            Bs[kq + 3][n] = b4.w;
        }
        __syncthreads();
#pragma unroll
        for (int kk = 0; kk < 16; ++kk) {
            float4 a4 = *(const float4*)&As[kk][ty * 4];
            float4 b4 = *(const float4*)&Bs[kk][tx * 4];
            float av[4] = {a4.x, a4.y, a4.z, a4.w};
            float bv2[4] = {b4.x, b4.y, b4.z, b4.w};
#pragma unroll
            for (int i = 0; i < 4; ++i)
#pragma unroll
                for (int j = 0; j < 4; ++j) acc[i][j] += av[i] * bv2[j];
        }
        __syncthreads();
    }
    float scl = (act == 2) ? *sclp : 0.f;
#pragma unroll
    for (int i = 0; i < 4; ++i) {
        int row = m0 + ty * 4 + i;
#pragma unroll
        for (int j = 0; j < 4; ++j) {
            int col = n0 + tx * 4 + j;
            if (col < N) {
                float v = acc[i][j];
                if (bias) v += bias[col];
                if (act == 1) v = fmaxf(v, 0.f);
                else if (act == 2) v = tanhf(v) * scl;
                C[(size_t)row * ldc + col] = v;
            }
        }
    }
}

// ---------------- fused sample + scores + softmax + aggregate ----------------
// 1 wave = 1 query. Lane l owns sample k=l (l<49). Block = 2 waves.
// LDS: per-wave bf16 copy of sampled[49][256] (row stride 258 bf16 = 129 uints).
__global__ __launch_bounds__(128) void k2_attn(
    const float* __restrict__ memT, const float* __restrict__ refb,
    const float* __restrict__ OFFb, const float* __restrict__ QKb,
    float* __restrict__ AGG, float* __restrict__ attnOut) {
    __shared__ unsigned samp[2][49 * 129];
    const int wid = threadIdx.x >> 6;
    const int lane = threadIdx.x & 63;
    int bid = blockIdx.x;
    // XCD swizzle: 2048 blocks -> 8 chunks of 256 (each XCD sees one batch-half)
    int swz = (bid & 7) * 256 + (bid >> 3);
    int qidx = swz * 2 + wid;
    const int qu = __builtin_amdgcn_readfirstlane(qidx);
    const int b = qu >> 10, n = qu & 1023;

    const float cx = refb[(size_t)qu * 4 + 0] * 2.f - 1.f;
    const float cy = refb[(size_t)qu * 4 + 1] * 2.f - 1.f;
    const bool act = lane < KK;
    float ox = 0.f, oy = 0.f;
    if (act) {
        float2 o2 = *(const float2*)&OFFb[(size_t)qu * 98 + 2 * lane];
        ox = o2.x;
        oy = o2.y;
    }
    int gxk = act ? (lane % 7) : 0, gyk = act ? (lane / 7) : 0;
    float sx = cx + (float)(gxk - 3) * (2.f / 63.f) + ox;
    float sy = cy + (float)(gyk - 3) * (2.f / 63.f) + oy;
    sx = fminf(fmaxf(sx, -1.f), 1.f);
    sy = fminf(fmaxf(sy, -1.f), 1.f);
    float xf = (sx + 1.f) * 31.5f, yf = (sy + 1.f) * 31.5f;
    float x0f = floorf(xf), y0f = floorf(yf);
    float fx = xf - x0f, fy = yf - y0f;
    int x0 = min(max((int)x0f, 0), 63), y0 = min(max((int)y0f, 0), 63);
    int x1 = min(x0 + 1, 63), y1 = min(y0 + 1, 63);
    float w00 = (1.f - fx) * (1.f - fy), w01 = fx * (1.f - fy);
    float w10 = (1.f - fx) * fy, w11 = fx * fy;
    const float* mb = memT + (size_t)b * HWP * DM;
    const float* p00 = mb + (size_t)(y0 * 64 + x0) * DM;
    const float* p01 = mb + (size_t)(y0 * 64 + x1) * DM;
    const float* p10 = mb + (size_t)(y1 * 64 + x0) * DM;
    const float* p11 = mb + (size_t)(y1 * 64 + x1) * DM;

    unsigned* srow = &samp[wid][lane * 129];
    const float* qk = QKb + (size_t)qu * 2048;
    float p[8];
#pragma unroll
    for (int h = 0; h < 8; ++h) p[h] = 0.f;

#pragma unroll 4
    for (int cc = 0; cc < 256; cc += 16) {
        float sv[16];
#pragma unroll
        for (int j = 0; j < 16; ++j) sv[j] = 0.f;
        if (act) {
#pragma unroll
            for (int j4 = 0; j4 < 16; j4 += 4) {
                float4 g0 = *(const float4*)(p00 + cc + j4);
                float4 g1 = *(const float4*)(p01 + cc + j4);
                float4 g2 = *(const float4*)(p10 + cc + j4);
                float4 g3 = *(const float4*)(p11 + cc + j4);
                sv[j4 + 0] = w00 * g0.x + w01 * g1.x + w10 * g2.x + w11 * g3.x;
                sv[j4 + 1] = w00 * g0.y + w01 * g1.y + w10 * g2.y + w11 * g3.y;
                sv[j4 + 2] = w00 * g0.z + w01 * g1.z + w10 * g2.z + w11 * g3.z;
                sv[j4 + 3] = w00 * g0.w + w01 * g1.w + w10 * g2.w + w11 * g3.w;
            }
#pragma unroll
            for (int tt = 0; tt < 8; ++tt)
                srow[cc / 2 + tt] = pack_bf16(sv[2 * tt], sv[2 * tt + 1]);
        }
        // wave-uniform QK loads (scalarized) + dot
#pragma unroll
        for (int h = 0; h < 8; ++h) {
            const float* qr = qk + h * 256 + cc;
            float4 qa = *(const float4*)(qr + 0);
            float4 qb = *(const float4*)(qr + 4);
            float4 qc = *(const float4*)(qr + 8);
            float4 qd = *(const float4*)(qr + 12);
            float a = p[h];
            a += sv[0] * qa.x + sv[1] * qa.y + sv[2] * qa.z + sv[3] * qa.w;
            a += sv[4] * qb.x + sv[5] * qb.y + sv[6] * qb.z + sv[7] * qb.w;
            a += sv[8] * qc.x + sv[9] * qc.y + sv[10] * qc.z + sv[11] * qc.w;
            a += sv[12] * qd.x + sv[13] * qd.y + sv[14] * qd.z + sv[15] * qd.w;
            p[h] = a;
        }
    }

    // softmax over k (lanes), per head
    const float scl = 0.17677669529663687f;  // 1/sqrt(32)
    float attn[8];
#pragma unroll
    for (int h = 0; h < 8; ++h) {
        float s = act ? p[h] * scl : -INFINITY;
        float m = s;
#pragma unroll
        for (int off = 32; off; off >>= 1) m = fmaxf(m, __shfl_xor(m, off));
        float e = act ? expf(s - m) : 0.f;
        float sum = e;
#pragma unroll
        for (int off = 32; off; off >>= 1) sum += __shfl_xor(sum, off);
        attn[h] = e / sum;
    }
    if (act) {
#pragma unroll
        for (int h = 0; h < 8; ++h)
            attnOut[((size_t)(b * 8 + h) * 1024 + n) * 49 + lane] = attn[h];
    }

    // aggregate: agg[h][c] = sum_k attn[h][k]*sampled[k][c]; lane owns c=4*lane..+3
    float a0[8], a1[8], a2[8], a3[8];
#pragma unroll
    for (int h = 0; h < 8; ++h) a0[h] = a1[h] = a2[h] = a3[h] = 0.f;
    const unsigned* sb = &samp[wid][0];
    for (int k = 0; k < KK; ++k) {
        unsigned u0 = sb[k * 129 + 2 * lane];
        unsigned u1 = sb[k * 129 + 2 * lane + 1];
        float s0 = __uint_as_float(u0 << 16);
        float s1 = __uint_as_float(u0 & 0xffff0000u);
        float s2 = __uint_as_float(u1 << 16);
        float s3 = __uint_as_float(u1 & 0xffff0000u);
#pragma unroll
        for (int h = 0; h < 8; ++h) {
            float av = __shfl(attn[h], k);
            a0[h] += av * s0;
            a1[h] += av * s1;
            a2[h] += av * s2;
            a3[h] += av * s3;
        }
    }
    float* aggr = AGG + (size_t)qu * 2048;
#pragma unroll
    for (int h = 0; h < 8; ++h) {
        float4 st;
        st.x = a0[h];
        st.y = a1[h];
        st.z = a2[h];
        st.w = a3[h];
        *(float4*)&aggr[h * 256 + 4 * lane] = st;
    }
}

extern "C" void kernel_launch(void* const* d_in, const int* in_sizes, int n_in,
                              void* d_out, int out_size, void* d_ws, size_t ws_size,
                              hipStream_t stream) {
    (void)in_sizes; (void)n_in; (void)out_size; (void)ws_size;
    const float* X     = (const float*)d_in[0];
    const float* refb  = (const float*)d_in[1];
    const float* mem   = (const float*)d_in[2];
    const float* Wq    = (const float*)d_in[3];
    const float* bq    = (const float*)d_in[4];
    const float* Wk    = (const float*)d_in[5];
    const float* Wv    = (const float*)d_in[7];
    const float* bv    = (const float*)d_in[8];
    const float* Wo    = (const float*)d_in[9];
    const float* bo    = (const float*)d_in[10];
    const float* Woff1 = (const float*)d_in[11];
    const float* boff1 = (const float*)d_in[12];
    const float* Woff2 = (const float*)d_in[13];
    const float* boff2 = (const float*)d_in[14];
    const float* sigma = (const float*)d_in[15];

    float* out  = (float*)d_out;
    float* attn = out + (size_t)BB * NQ1 * DM;  // (B,8,N,49)

    float* ws   = (float*)d_ws;
    float* memT = ws;                  // 4,194,304
    float* Qb   = ws + 4194304;        // 1,048,576
    float* Hb   = ws + 5242880;        // 1,048,576
    float* OFFb = ws + 6291456;        //   401,408
    float* QKb  = ws + 6692864;        // 8,388,608
    float* AGGb = ws + 15081472;       // 8,388,608
    float* OHb  = ws + 23470080;       // 1,048,576  (total ~93.5 MB)

    // 1) memory transpose
    k_transpose<<<dim3(128, 8, 4), dim3(32, 8), 0, stream>>>(mem, memT);
    // 2) Q = X@Wq + bq
    gemm_f32<<<dim3(4, 64, 1), 256, 0, stream>>>(X, Wq, bq, Qb,
        NQT, 256, 256, 256, 256, 256, 0, 0, 0, 0, nullptr, 0, 0);
    // 3) H = relu(X@Woff1 + boff1)
    gemm_f32<<<dim3(4, 64, 1), 256, 0, stream>>>(X, Woff1, boff1, Hb,
        NQT, 256, 256, 256, 256, 256, 0, 0, 0, 0, nullptr, 1, 0);
    // 4) OFF = tanh(H@Woff2 + boff2)*sigma   (N=98)
    gemm_f32<<<dim3(2, 64, 1), 256, 0, stream>>>(Hb, Woff2, boff2, OFFb,
        NQT, 98, 256, 256, 98, 98, 0, 0, 0, 0, sigma, 2, 0);
    // 5) QK[n, h*256+c] = sum_j Q[n,h*32+j]*Wk[c,h*32+j]   (batched over h, B^T)
    gemm_f32<<<dim3(4, 64, 8), 256, 0, stream>>>(Qb, Wk, nullptr, QKb,
        NQT, 256, 32, 256, 256, 2048, 32, 32, 256, 0, nullptr, 0, 1);
    // 6) fused sampling + scores + softmax + aggregate
    k2_attn<<<2048, 128, 0, stream>>>(memT, refb, OFFb, QKb, AGGb, attn);
    // 7) OH[n, h*32+j] = sum_c AGG[n,h*256+c]*Wv[c,h*32+j] + bv  (batched, N=32)
    gemm_f32<<<dim3(1, 64, 8), 256, 0, stream>>>(AGGb, Wv, bv, OHb,
        NQT, 32, 256, 2048, 256, 256, 256, 32, 32, 32, nullptr, 0, 0);
    // 8) out = OH@Wo + bo
    gemm_f32<<<dim3(4, 64, 1), 256, 0, stream>>>(OHb, Wo, bo, out,
        NQT, 256, 256, 256, 256, 256, 0, 0, 0, 0, nullptr, 0, 0);
}